// Round 7
// baseline (44.994 us; speedup 1.0000x reference)
//
#include <hip/hip_runtime.h>
#include <hip/hip_bf16.h>

// Shapes (fixed): D=1, S=64, A=128, P=K=6, T=80
#define NS 64
#define NA 128
#define NK 6
#define NT 80
#define THREADS 256
#define TILE_A 4
#define NR (TILE_A * NK)     // 24 rows

// Output layout (flat concat, float):
//   waymo_valid  [S,T,A]        655360
//   waymo_trajs  [S,T,A,K,2]    7864320
//   waymo_scores [S,A,K]        49152
//   waymo_yaw    [S,T,A,K,1]    3932160
#define OFF_TRAJ   655360
#define OFF_SCORE  (655360 + 7864320)
#define OFF_YAW    (655360 + 7864320 + 49152)

#define PS_T 26   // sP per-t stride in float2 (even -> 16B-aligned b128 reads)
#define YS_T 28   // sY per-t stride in float  (mult of 4 -> 16B-aligned b128 reads)

typedef float nfloat4 __attribute__((ext_vector_type(4)));

__global__ __launch_bounds__(THREADS) void waymo_post_kernel(
    const int*    __restrict__ validIn,  // [S,A] (bool -> int32)
    const float*  __restrict__ confIn,   // [1,S,A,K]
    const float2* __restrict__ posIn,    // [1,S,A,K,T] float2
    const float*  __restrict__ yawIn,    // [1,S,A,K,T]
    const float*  __restrict__ typeIn,   // [S,A,3] one-hot
    float*        __restrict__ out)
{
    const int s   = blockIdx.y;
    const int a0  = blockIdx.x * TILE_A;
    const int tid = threadIdx.x;

    __shared__ float2 sP[NT * PS_T];  // [t][row], 16640 B
    __shared__ float  sY[NT * YS_T];  // [t][row],  8960 B

    const size_t sa0 = (size_t)s * NA + a0;
    const float2* pbase = posIn + sa0 * (NK * NT);
    const float*  ybase = yawIn + sa0 * (NK * NT);

    // ---- stage pos: 960 f4 (contiguous 15 KB), transpose into [t][row] ----
    for (int i = tid; i < NR * (NT / 2); i += THREADS) {
        int r = i / 40, q = i - r * 40;
        nfloat4 v = *(const nfloat4*)(pbase + (size_t)r * NT + 2 * q);
        sP[(2 * q + 0) * PS_T + r] = float2{v.x, v.y};
        sP[(2 * q + 1) * PS_T + r] = float2{v.z, v.w};
    }
    // ---- stage yaw: 480 f4 (contiguous 7.5 KB), transpose into [t][row] ----
    for (int i = tid; i < NR * (NT / 4); i += THREADS) {
        int r = i / 20, m = i - r * 20;
        nfloat4 v = *(const nfloat4*)(ybase + (size_t)r * NT + 4 * m);
        sY[(4 * m + 0) * YS_T + r] = v.x;
        sY[(4 * m + 1) * YS_T + r] = v.y;
        sY[(4 * m + 2) * YS_T + r] = v.z;
        sY[(4 * m + 3) * YS_T + r] = v.w;
    }
    __syncthreads();

    if (tid < 32 * TILE_A) {
        // ================= SCORE ROLE: waves 0..1 (32 lanes/agent) =================
        const int la   = tid >> 5;
        const int lane = tid & 31;
        const int a    = a0 + la;
        const int p    = lane >> 1;   // pair slot 0..15 (15 used)
        const int half = lane & 1;    // time half

        const size_t sa = (size_t)s * NA + a;
        const float th = 2.5f * typeIn[sa * 3 + 0]
                       + 1.0f * typeIn[sa * 3 + 1]
                       + 1.5f * typeIn[sa * 3 + 2];

        int pi, pj;
        if      (p < 5)  { pi = 0; pj = p + 1; }
        else if (p < 9)  { pi = 1; pj = p - 3; }
        else if (p < 12) { pi = 2; pj = p - 6; }
        else if (p < 14) { pi = 3; pj = p - 8; }
        else             { pi = 4; pj = 5;     }

        const int rI = la * NK + pi, rJ = la * NK + pj;
        float dsum = 0.f;
        for (int t = half * 40; t < half * 40 + 40; ++t) {
            float2 u = sP[t * PS_T + rI];
            float2 v = sP[t * PS_T + rJ];
            float dx = u.x - v.x, dy = u.y - v.y;
            dsum += sqrtf(dx * dx + dy * dy);
        }
        dsum += __shfl_xor(dsum, 1);
        const bool within = (dsum / 80.0f) < th;
        const bool predb  = (half == 0) && (p < 15) && within;
        unsigned long long bal = __ballot(predb);
        unsigned mask32 = (unsigned)(bal >> (tid & 32));  // this agent's 32 bits

        if (lane == 0) {
            // softmax over K=6 (stable) + renorm
            float c[NK];
            float mx = -3e38f;
            for (int q = 0; q < NK; ++q) { c[q] = confIn[sa * NK + q]; mx = fmaxf(mx, c[q]); }
            float ssum = 0.f;
            for (int q = 0; q < NK; ++q) { c[q] = expf(c[q] - mx); ssum += c[q]; }
            for (int q = 0; q < NK; ++q) c[q] /= ssum;
            ssum = 0.f;
            for (int q = 0; q < NK; ++q) ssum += c[q];
            for (int q = 0; q < NK; ++q) c[q] /= ssum;

            // stable descending argsort (selection; strict > keeps earliest on ties)
            int ord[NK]; bool used[NK];
            for (int q = 0; q < NK; ++q) used[q] = false;
            for (int st = 0; st < NK; ++st) {
                int best = 0; float bv = -3e38f;
                for (int q = 0; q < NK; ++q)
                    if (!used[q] && c[q] > bv) { bv = c[q]; best = q; }
                used[best] = true; ord[st] = best;
            }

            float cur[NK];
            for (int q = 0; q < NK; ++q) cur[q] = c[q];

            if (validIn[sa] != 0) {
                for (int st = 0; st < NK; ++st) {
                    int k = ord[st];
                    float ck = cur[k];
                    bool any = false;
                    for (int j = 0; j < NK; ++j) {
                        if (j == k) continue;
                        int lo = j < k ? j : k;
                        int hi = j < k ? k : j;
                        int pidx = lo * 5 - (lo * (lo - 1)) / 2 + (hi - lo - 1);
                        if (((mask32 >> (2 * pidx)) & 1u) && (cur[j] > ck)) any = true;
                    }
                    if (any) cur[k] = 0.001f;
                }
            }

            // renormalize, then softmax(log(s)/0.5) == s^2 / sum(s^2)
            float tsum = 0.f;
            for (int q = 0; q < NK; ++q) tsum += cur[q];
            float w[NK]; float wsum = 0.f;
            for (int q = 0; q < NK; ++q) {
                float qq = cur[q] / tsum;
                w[q] = qq * qq; wsum += w[q];
            }
            float* outSc = out + OFF_SCORE;
            for (int q = 0; q < NK; ++q) outSc[sa * NK + q] = w[q] / wsum;
        }
    } else {
        // ================= STORE ROLE: waves 2..3 (128 threads) =================
        const int o2 = tid - 128;

        // valid out: per t, 4 agents -> 1 float4 (80 stores)
        if (o2 < NT) {
            int t = o2;
            nfloat4 v;
            v.x = (validIn[sa0 + 0] != 0) ? 1.0f : 0.0f;
            v.y = (validIn[sa0 + 1] != 0) ? 1.0f : 0.0f;
            v.z = (validIn[sa0 + 2] != 0) ? 1.0f : 0.0f;
            v.w = (validIn[sa0 + 3] != 0) ? 1.0f : 0.0f;
            size_t f4 = (size_t)(s * NT + t) * (NA / 4) + (a0 >> 2);
            __builtin_nontemporal_store(v, (nfloat4*)out + f4);
        }

        // traj out: per t, 24 f2 -> 12 f4 (contiguous 192B run), 960 stores
        nfloat4* trajOut = (nfloat4*)(out + OFF_TRAJ);
        for (int o = o2; o < NT * 12; o += 128) {
            int t = o / 12, j = o - (o / 12) * 12;
            nfloat4 v = *(const nfloat4*)&sP[t * PS_T + 2 * j];
            size_t f4 = (size_t)(s * NT + t) * (NA * NK / 2) + a0 * 3 + j;
            __builtin_nontemporal_store(v, trajOut + f4);
        }

        // yaw out: per t, 24 floats -> 6 f4 (96B run), 480 stores
        nfloat4* yawOut = (nfloat4*)(out + OFF_YAW);
        for (int o = o2; o < NT * 6; o += 128) {
            int t = o / 6, j = o - (o / 6) * 6;
            nfloat4 v = *(const nfloat4*)&sY[t * YS_T + 4 * j];
            size_t f4 = (size_t)(s * NT + t) * (NA * NK / 4) + ((a0 * 6) >> 2) + j;
            __builtin_nontemporal_store(v, yawOut + f4);
        }
    }
}

extern "C" void kernel_launch(void* const* d_in, const int* in_sizes, int n_in,
                              void* d_out, int out_size, void* d_ws, size_t ws_size,
                              hipStream_t stream) {
    const int*    validIn = (const int*)d_in[0];
    const float*  confIn  = (const float*)d_in[1];
    const float2* posIn   = (const float2*)d_in[2];
    const float*  yawIn   = (const float*)d_in[3];
    const float*  typeIn  = (const float*)d_in[4];
    float* out = (float*)d_out;

    dim3 grid(NA / TILE_A, NS);   // (32, 64) = 2048 blocks
    waymo_post_kernel<<<grid, THREADS, 0, stream>>>(
        validIn, confIn, posIn, yawIn, typeIn, out);
}

// Round 8
// 42.392 us; speedup vs baseline: 1.0614x; 1.0614x over previous
//
#include <hip/hip_runtime.h>
#include <hip/hip_bf16.h>

// Shapes (fixed): D=1, S=64, A=128, P=K=6, T=80
#define NS 64
#define NA 128
#define NK 6
#define NT 80
#define HT 40                 // timesteps per pass
#define THREADS 256
#define TILE_A 4
#define NR (TILE_A * NK)      // 24 rows

// Output layout (flat concat, float):
//   waymo_valid  [S,T,A]        655360
//   waymo_trajs  [S,T,A,K,2]    7864320
//   waymo_scores [S,A,K]        49152
//   waymo_yaw    [S,T,A,K,1]    3932160
#define OFF_TRAJ   655360
#define OFF_SCORE  (655360 + 7864320)
#define OFF_YAW    (655360 + 7864320 + 49152)

#define SP 42   // float2 row stride (pos half-tile): 336B/row, 16B-aligned
#define SY 44   // float  row stride (yaw half-tile): 176B/row, 16B-aligned

typedef float nfloat4 __attribute__((ext_vector_type(4)));

__global__ __launch_bounds__(THREADS) void waymo_post_kernel(
    const int*    __restrict__ validIn,  // [S,A] (bool -> int32)
    const float*  __restrict__ confIn,   // [1,S,A,K]
    const float2* __restrict__ posIn,    // [1,S,A,K,T] float2
    const float*  __restrict__ yawIn,    // [1,S,A,K,T]
    const float*  __restrict__ typeIn,   // [S,A,3] one-hot
    float*        __restrict__ out)
{
    const int s   = blockIdx.y;
    const int a0  = blockIdx.x * TILE_A;
    const int tid = threadIdx.x;

    __shared__ float2 sP[NR * SP];  // 8064 B, row-major [row][t-local]
    __shared__ float  sY[NR * SY];  // 4224 B

    const size_t sa0 = (size_t)s * NA + a0;
    const float2* pbase = posIn + sa0 * (NK * NT);
    const float*  ybase = yawIn + sa0 * (NK * NT);

    // ---- score-role per-thread constants (waves 0..1: 32 lanes/agent) ----
    const int la   = tid >> 5;
    const int lane = tid & 31;
    const int p    = lane >> 1;   // pair slot 0..15 (15 used)
    const int half = lane & 1;    // 20-t sub-half within each pass
    int pi, pj;
    if      (p < 5)  { pi = 0; pj = p + 1; }
    else if (p < 9)  { pi = 1; pj = p - 3; }
    else if (p < 12) { pi = 2; pj = p - 6; }
    else if (p < 14) { pi = 3; pj = p - 8; }
    else             { pi = 4; pj = 5;     }
    const int rI = la * NK + pi, rJ = la * NK + pj;
    float dsum = 0.f;

    nfloat4* trajOut = (nfloat4*)(out + OFF_TRAJ);
    nfloat4* yawOut  = (nfloat4*)(out + OFF_YAW);

    for (int h = 0; h < 2; ++h) {
        // ---- stage pos: 480 f4, contiguous 320B runs per row-half ----
        for (int i = tid; i < NR * (HT / 2); i += THREADS) {
            int r = i / 20, q = i - r * 20;
            nfloat4 v = *(const nfloat4*)(pbase + (size_t)r * NT + h * HT + 2 * q);
            *(nfloat4*)&sP[r * SP + 2 * q] = v;
        }
        // ---- stage yaw: 240 f4, contiguous 160B runs per row-half ----
        for (int i = tid; i < NR * (HT / 4); i += THREADS) {
            int r = i / 10, m = i - r * 10;
            nfloat4 v = *(const nfloat4*)(ybase + (size_t)r * NT + h * HT + 4 * m);
            *(nfloat4*)&sY[r * SY + 4 * m] = v;
        }
        __syncthreads();

        if (tid < 128) {
            // ---- score partial: 20 t-local per lane, accumulate across passes ----
            for (int tl = half * 20; tl < half * 20 + 20; ++tl) {
                float2 u = sP[rI * SP + tl];
                float2 v = sP[rJ * SP + tl];
                float dx = u.x - v.x, dy = u.y - v.y;
                dsum += sqrtf(dx * dx + dy * dy);
            }
        } else {
            const int o2 = tid - 128;

            // valid out (h==0 only): per t, 4 agents -> 1 float4
            if (h == 0 && o2 < NT) {
                int t = o2;
                nfloat4 v;
                v.x = (validIn[sa0 + 0] != 0) ? 1.0f : 0.0f;
                v.y = (validIn[sa0 + 1] != 0) ? 1.0f : 0.0f;
                v.z = (validIn[sa0 + 2] != 0) ? 1.0f : 0.0f;
                v.w = (validIn[sa0 + 3] != 0) ? 1.0f : 0.0f;
                size_t f4 = (size_t)(s * NT + t) * (NA / 4) + (a0 >> 2);
                __builtin_nontemporal_store(v, (nfloat4*)out + f4);
            }

            // traj out: per t-local, 24 f2 -> 12 f4 (192B run); 480 f4/pass
            for (int o = o2; o < HT * 12; o += 128) {
                int tl = o / 12, j = o - (o / 12) * 12;
                float2 u = sP[(2 * j + 0) * SP + tl];
                float2 w = sP[(2 * j + 1) * SP + tl];
                nfloat4 v{u.x, u.y, w.x, w.y};
                size_t f4 = (size_t)(s * NT + h * HT + tl) * (NA * NK / 2) + a0 * 3 + j;
                __builtin_nontemporal_store(v, trajOut + f4);
            }

            // yaw out: per t-local, 24 f -> 6 f4 (96B run); 240 f4/pass
            for (int o = o2; o < HT * 6; o += 128) {
                int tl = o / 6, j = o - (o / 6) * 6;
                nfloat4 v{sY[(4 * j + 0) * SY + tl],
                          sY[(4 * j + 1) * SY + tl],
                          sY[(4 * j + 2) * SY + tl],
                          sY[(4 * j + 3) * SY + tl]};
                size_t f4 = (size_t)(s * NT + h * HT + tl) * (NA * NK / 4) + ((a0 * 6) >> 2) + j;
                __builtin_nontemporal_store(v, yawOut + f4);
            }
        }
        if (h == 0) __syncthreads();   // protect LDS before pass-2 staging
    }

    // ---- score finalize: waves 0..1 only (verified NMS tail) ----
    if (tid < 128) {
        dsum += __shfl_xor(dsum, 1);
        const int a = a0 + la;
        const size_t sa = (size_t)s * NA + a;
        const float th = 2.5f * typeIn[sa * 3 + 0]
                       + 1.0f * typeIn[sa * 3 + 1]
                       + 1.5f * typeIn[sa * 3 + 2];
        const bool within = (dsum / 80.0f) < th;
        const bool predb  = (half == 0) && (p < 15) && within;
        unsigned long long bal = __ballot(predb);
        unsigned mask32 = (unsigned)(bal >> (tid & 32));  // this agent's 32 bits

        if (lane == 0) {
            // softmax over K=6 (stable) + renorm
            float c[NK];
            float mx = -3e38f;
            for (int q = 0; q < NK; ++q) { c[q] = confIn[sa * NK + q]; mx = fmaxf(mx, c[q]); }
            float ssum = 0.f;
            for (int q = 0; q < NK; ++q) { c[q] = expf(c[q] - mx); ssum += c[q]; }
            for (int q = 0; q < NK; ++q) c[q] /= ssum;
            ssum = 0.f;
            for (int q = 0; q < NK; ++q) ssum += c[q];
            for (int q = 0; q < NK; ++q) c[q] /= ssum;

            // stable descending argsort (selection; strict > keeps earliest on ties)
            int ord[NK]; bool used[NK];
            for (int q = 0; q < NK; ++q) used[q] = false;
            for (int st = 0; st < NK; ++st) {
                int best = 0; float bv = -3e38f;
                for (int q = 0; q < NK; ++q)
                    if (!used[q] && c[q] > bv) { bv = c[q]; best = q; }
                used[best] = true; ord[st] = best;
            }

            float cur[NK];
            for (int q = 0; q < NK; ++q) cur[q] = c[q];

            if (validIn[sa] != 0) {
                for (int st = 0; st < NK; ++st) {
                    int k = ord[st];
                    float ck = cur[k];
                    bool any = false;
                    for (int j = 0; j < NK; ++j) {
                        if (j == k) continue;
                        int lo = j < k ? j : k;
                        int hi = j < k ? k : j;
                        int pidx = lo * 5 - (lo * (lo - 1)) / 2 + (hi - lo - 1);
                        if (((mask32 >> (2 * pidx)) & 1u) && (cur[j] > ck)) any = true;
                    }
                    if (any) cur[k] = 0.001f;
                }
            }

            // renormalize, then softmax(log(s)/0.5) == s^2 / sum(s^2)
            float tsum = 0.f;
            for (int q = 0; q < NK; ++q) tsum += cur[q];
            float w[NK]; float wsum = 0.f;
            for (int q = 0; q < NK; ++q) {
                float qq = cur[q] / tsum;
                w[q] = qq * qq; wsum += w[q];
            }
            float* outSc = out + OFF_SCORE;
            for (int q = 0; q < NK; ++q) outSc[sa * NK + q] = w[q] / wsum;
        }
    }
}

extern "C" void kernel_launch(void* const* d_in, const int* in_sizes, int n_in,
                              void* d_out, int out_size, void* d_ws, size_t ws_size,
                              hipStream_t stream) {
    const int*    validIn = (const int*)d_in[0];
    const float*  confIn  = (const float*)d_in[1];
    const float2* posIn   = (const float2*)d_in[2];
    const float*  yawIn   = (const float*)d_in[3];
    const float*  typeIn  = (const float*)d_in[4];
    float* out = (float*)d_out;

    dim3 grid(NA / TILE_A, NS);   // (32, 64) = 2048 blocks
    waymo_post_kernel<<<grid, THREADS, 0, stream>>>(
        validIn, confIn, posIn, yawIn, typeIn, out);
}

// Round 9
// 38.301 us; speedup vs baseline: 1.1747x; 1.1068x over previous
//
#include <hip/hip_runtime.h>
#include <hip/hip_bf16.h>

// Shapes (fixed): D=1, S=64, A=128, P=K=6, T=80
#define NS 64
#define NA 128
#define NK 6
#define NT 80
#define THREADS 512
#define TILE_A 8
#define NROWS (TILE_A * NK)   // 48

// Output layout (flat concat, float):
//   waymo_valid  [S,T,A]        655360
//   waymo_trajs  [S,T,A,K,2]    7864320
//   waymo_scores [S,A,K]        49152
//   waymo_yaw    [S,T,A,K,1]    3932160
#define OFF_TRAJ   655360
#define OFF_SCORE  (655360 + 7864320)
#define OFF_YAW    (655360 + 7864320 + 49152)

#define PSTRIDE 82   // float2 row stride for pos (16B-aligned rows)
#define YSTRIDE 84   // float  row stride for yaw (16B-aligned rows)

typedef float nfloat4 __attribute__((ext_vector_type(4)));

__global__ __launch_bounds__(THREADS) void waymo_post_kernel(
    const int*    __restrict__ validIn,  // [S,A] (bool -> int32)
    const float*  __restrict__ confIn,   // [1,S,A,K]
    const float2* __restrict__ posIn,    // [1,S,A,K,T] float2
    const float*  __restrict__ yawIn,    // [1,S,A,K,T]
    const float*  __restrict__ typeIn,   // [S,A,3] one-hot
    float*        __restrict__ out)
{
    const int g   = blockIdx.x;          // 0..1023
    const int tid = threadIdx.x;
    const int s   = g >> 4;
    const int a0  = (g & 15) * TILE_A;

    __shared__ float2 sPos[NROWS * PSTRIDE];  // [row][t], 31.5 KB
    __shared__ float  sYaw[NROWS * YSTRIDE];  // [row][t], 15.75 KB

    const size_t sa0 = (size_t)s * NA + a0;
    const float2* pbase = posIn + sa0 * (NK * NT);
    const float*  ybase = yawIn + sa0 * (NK * NT);

    // ---- stage pos: 1920 float4, fully contiguous 30 KB range ----
    for (int i = tid; i < NROWS * (NT / 2); i += THREADS) {  // 40 float4/row
        int r = i / 40, q = i - r * 40;
        nfloat4 v = *(const nfloat4*)(pbase + (size_t)r * NT + 2 * q);
        *(nfloat4*)&sPos[r * PSTRIDE + 2 * q] = v;
    }
    // ---- stage yaw: 960 float4, contiguous 15 KB range ----
    for (int i = tid; i < NROWS * (NT / 4); i += THREADS) {  // 20 float4/row
        int r = i / 20, m = i - r * 20;
        nfloat4 v = *(const nfloat4*)(ybase + (size_t)r * NT + 4 * m);
        *(nfloat4*)&sYaw[r * YSTRIDE + 4 * m] = v;
    }
    __syncthreads();

    float* outSc = out + OFF_SCORE;

    // ---- score + NMS: waves 0..3 (32 lanes/agent); waves 4..7 skip ahead ----
    if (tid < 256) {
        const int la   = tid >> 5;
        const int lane = tid & 31;
        const int a    = a0 + la;
        const int p    = lane >> 1;   // pair slot 0..15 (15 used)
        const int half = lane & 1;    // time half

        const size_t sa = (size_t)s * NA + a;
        const float th = 2.5f * typeIn[sa * 3 + 0]
                       + 1.0f * typeIn[sa * 3 + 1]
                       + 1.5f * typeIn[sa * 3 + 2];

        int pi, pj;
        if      (p < 5)  { pi = 0; pj = p + 1; }
        else if (p < 9)  { pi = 1; pj = p - 3; }
        else if (p < 12) { pi = 2; pj = p - 6; }
        else if (p < 14) { pi = 3; pj = p - 8; }
        else             { pi = 4; pj = 5;     }

        const int rI = la * NK + pi, rJ = la * NK + pj;
        float dsum = 0.f;
        for (int t = half * 40; t < half * 40 + 40; ++t) {
            float2 u = sPos[rI * PSTRIDE + t];
            float2 v = sPos[rJ * PSTRIDE + t];
            float dx = u.x - v.x, dy = u.y - v.y;
            dsum += sqrtf(dx * dx + dy * dy);
        }
        dsum += __shfl_xor(dsum, 1);
        const bool within = (dsum / 80.0f) < th;
        const bool predb  = (half == 0) && (p < 15) && within;
        unsigned long long bal = __ballot(predb);
        unsigned mask32 = (unsigned)(bal >> (tid & 32));  // this agent's 32 bits

        if (lane == 0) {
            // softmax over K=6 (stable) + renorm
            float c[NK];
            float mx = -3e38f;
            for (int q = 0; q < NK; ++q) { c[q] = confIn[sa * NK + q]; mx = fmaxf(mx, c[q]); }
            float ssum = 0.f;
            for (int q = 0; q < NK; ++q) { c[q] = expf(c[q] - mx); ssum += c[q]; }
            for (int q = 0; q < NK; ++q) c[q] /= ssum;
            ssum = 0.f;
            for (int q = 0; q < NK; ++q) ssum += c[q];
            for (int q = 0; q < NK; ++q) c[q] /= ssum;

            // stable descending argsort (selection; strict > keeps earliest on ties)
            int ord[NK]; bool used[NK];
            for (int q = 0; q < NK; ++q) used[q] = false;
            for (int st = 0; st < NK; ++st) {
                int best = 0; float bv = -3e38f;
                for (int q = 0; q < NK; ++q)
                    if (!used[q] && c[q] > bv) { bv = c[q]; best = q; }
                used[best] = true; ord[st] = best;
            }

            float cur[NK];
            for (int q = 0; q < NK; ++q) cur[q] = c[q];

            if (validIn[sa] != 0) {
                for (int st = 0; st < NK; ++st) {
                    int k = ord[st];
                    float ck = cur[k];
                    bool any = false;
                    for (int j = 0; j < NK; ++j) {
                        if (j == k) continue;
                        int lo = j < k ? j : k;
                        int hi = j < k ? k : j;
                        int pidx = lo * 5 - (lo * (lo - 1)) / 2 + (hi - lo - 1);
                        if (((mask32 >> (2 * pidx)) & 1u) && (cur[j] > ck)) any = true;
                    }
                    if (any) cur[k] = 0.001f;
                }
            }

            // renormalize, then softmax(log(s)/0.5) == s^2 / sum(s^2)
            float tsum = 0.f;
            for (int q = 0; q < NK; ++q) tsum += cur[q];
            float w[NK]; float wsum = 0.f;
            for (int q = 0; q < NK; ++q) {
                float qq = cur[q] / tsum;
                w[q] = qq * qq; wsum += w[q];
            }
            for (int q = 0; q < NK; ++q) outSc[sa * NK + q] = w[q] / wsum;
        }
    }

    // ---- traj out: per t, 48 rows (float2) -> 24 float4 (384B runs), 1920 float4 ----
    nfloat4* trajOut = (nfloat4*)(out + OFF_TRAJ);
    for (int o = tid; o < NT * 24; o += THREADS) {
        int t = o / 24, j = o - (o / 24) * 24;
        float2 u = sPos[(2 * j + 0) * PSTRIDE + t];
        float2 w = sPos[(2 * j + 1) * PSTRIDE + t];
        nfloat4 v{u.x, u.y, w.x, w.y};
        size_t f4 = (((size_t)(s * NT + t) * NA + a0) * NK) >> 1;
        trajOut[f4 + j] = v;
    }
    // ---- yaw out: per t, 48 rows (float) -> 12 float4 (192B runs), 960 float4 ----
    nfloat4* yawOut = (nfloat4*)(out + OFF_YAW);
    for (int o = tid; o < NT * 12; o += THREADS) {
        int t = o / 12, j = o - (o / 12) * 12;
        nfloat4 v{sYaw[(4 * j + 0) * YSTRIDE + t],
                  sYaw[(4 * j + 1) * YSTRIDE + t],
                  sYaw[(4 * j + 2) * YSTRIDE + t],
                  sYaw[(4 * j + 3) * YSTRIDE + t]};
        size_t f4 = (((size_t)(s * NT + t) * NA + a0) * NK) >> 2;
        yawOut[f4 + j] = v;
    }
    // ---- valid out: per t, 8 agents -> 2 float4, 160 float4 ----
    if (tid < 160) {
        int t = tid >> 1, q = tid & 1;
        nfloat4 v;
        v.x = (validIn[sa0 + 4 * q + 0] != 0) ? 1.0f : 0.0f;
        v.y = (validIn[sa0 + 4 * q + 1] != 0) ? 1.0f : 0.0f;
        v.z = (validIn[sa0 + 4 * q + 2] != 0) ? 1.0f : 0.0f;
        v.w = (validIn[sa0 + 4 * q + 3] != 0) ? 1.0f : 0.0f;
        size_t f4 = ((size_t)(s * NT + t) * NA + a0) >> 2;
        ((nfloat4*)out)[f4 + q] = v;
    }
}

extern "C" void kernel_launch(void* const* d_in, const int* in_sizes, int n_in,
                              void* d_out, int out_size, void* d_ws, size_t ws_size,
                              hipStream_t stream) {
    const int*    validIn = (const int*)d_in[0];
    const float*  confIn  = (const float*)d_in[1];
    const float2* posIn   = (const float2*)d_in[2];
    const float*  yawIn   = (const float*)d_in[3];
    const float*  typeIn  = (const float*)d_in[4];
    float* out = (float*)d_out;

    waymo_post_kernel<<<NS * (NA / TILE_A), THREADS, 0, stream>>>(
        validIn, confIn, posIn, yawIn, typeIn, out);
}